// Round 8
// baseline (458.876 us; speedup 1.0000x reference)
//
#include <hip/hip_runtime.h>

#define T_TOKENS 8192
#define IN_F 4096
#define OUT_F 11008

#define BM 256
#define BN 256
#define NT (IN_F / 64)   // 64 K-tiles of 64 (two k32-slices each)

typedef __attribute__((ext_vector_type(4))) int v4i;
typedef __attribute__((ext_vector_type(16))) int v16i;

__device__ __forceinline__ void load_lds16(const signed char* g, const signed char* l) {
    __builtin_amdgcn_global_load_lds(
        (const __attribute__((address_space(1))) void*)g,
        (__attribute__((address_space(3))) void*)l, 16, 0, 0);
}

// Fragment-major layout for both operands:
//   buf[blk32][k32][lane][16B], lane = hi*32 + l31, holding
//   src[blk*32 + l31][k32*32 + hi*16 .. +16]   (16 int8)
// Byte-identical to the mfma_i32_32x32x32_i8 A/B fragment per lane.

// ------------- Pass 1: fused quant (frag-major xq) + weight repack -------------
__global__ __launch_bounds__(256) void quant_repack_kernel(
        const float* __restrict__ x, signed char* __restrict__ xq,
        float* __restrict__ qscale, const int* __restrict__ w32,
        signed char* __restrict__ w8) {
    if (blockIdx.x < T_TOKENS) {
        const int row = blockIdx.x;
        const int t = threadIdx.x;
        const float4* xr = (const float4*)(x + (size_t)row * IN_F) + t * 4;
        float4 v[4];
        float am = 0.f;
#pragma unroll
        for (int i = 0; i < 4; ++i) {
            v[i] = xr[i];
            am = fmaxf(am, fmaxf(fmaxf(fabsf(v[i].x), fabsf(v[i].y)),
                                 fmaxf(fabsf(v[i].z), fabsf(v[i].w))));
        }
#pragma unroll
        for (int off = 32; off > 0; off >>= 1)
            am = fmaxf(am, __shfl_xor(am, off, 64));
        __shared__ float wmax[4];
        const int wv = t >> 6;
        if ((t & 63) == 0) wmax[wv] = am;
        __syncthreads();
        float amax = fmaxf(fmaxf(wmax[0], wmax[1]), fmaxf(wmax[2], wmax[3]));
        float qs = amax * (1.0f / 127.0f);
        if (qs < 1e-30f) qs = 1e-30f;
        const float inv = 1.0f / qs;
        if (t == 0) qscale[row] = qs;
        int q[16];
#pragma unroll
        for (int i = 0; i < 4; ++i) {
            q[i * 4 + 0] = max(-128, min(127, (int)rintf(v[i].x * inv)));
            q[i * 4 + 1] = max(-128, min(127, (int)rintf(v[i].y * inv)));
            q[i * 4 + 2] = max(-128, min(127, (int)rintf(v[i].z * inv)));
            q[i * 4 + 3] = max(-128, min(127, (int)rintf(v[i].w * inv)));
        }
        v4i p;
#pragma unroll
        for (int i = 0; i < 4; ++i)
            p[i] = (q[i * 4] & 255) | ((q[i * 4 + 1] & 255) << 8) |
                   ((q[i * 4 + 2] & 255) << 16) | ((q[i * 4 + 3] & 255) << 24);
        const int k32 = t >> 1, hi = t & 1;
        *(v4i*)(xq + (((size_t)(row >> 5)) * 128 + k32) * 1024 +
                ((hi * 32) + (row & 31)) * 16) = p;
    } else {
        const int bb = blockIdx.x - T_TOKENS;
        const int nblk = bb >> 5;
        const int kg = bb & 31;
        const int t = threadIdx.x;
        __shared__ signed char tile[32][144];
        const int rrow = t >> 3, c8 = t & 7;
        const int* src = w32 + (size_t)(nblk * 32 + rrow) * IN_F + kg * 128 + c8 * 16;
        v4i pk;
#pragma unroll
        for (int j = 0; j < 4; ++j) {
            v4i w = ((const v4i*)src)[j];
            pk[j] = (w[0] & 255) | ((w[1] & 255) << 8) |
                    ((w[2] & 255) << 16) | ((w[3] & 255) << 24);
        }
        *(v4i*)&tile[rrow][c8 * 16] = pk;
        __syncthreads();
        const int k32l = t >> 6, lane = t & 63;
        const int hi = lane >> 5, l31 = lane & 31;
        v4i o = *(const v4i*)&tile[l31][k32l * 32 + hi * 16];
        *(v4i*)(w8 + ((size_t)(nblk)*128 + kg * 4 + k32l) * 1024 + lane * 16) = o;
    }
}

// ------------- Pass 2: int8 GEMM, 4 waves x (128x128), ring-5 depth-4 -------
// Block 256x256, 4 waves (2x2), per-wave 128x128 via acc[4][4] (256 AGPR).
// LDS: ring of 5 x 32KB bufs (full 160KB), frag-major (conflict-free b128
// reads, linear gload_lds). Phase p: stage tile p+4 -> s_waitcnt vmcnt(24)
// lgkmcnt(0) -> barrier -> ds_read frags(p+1) + 32 MFMA of tile p.
// Depth-4 prefetch = 3-tile slack (~1860 cyc) covers HBM-latency B staging.
// Ring write/read race: buf read at phase r is rewritten at r+2; the
// lgkm(0)-before-barrier at r+1 drains the reads first (1-barrier proof).
__global__ __launch_bounds__(256, 1) void gemm_kernel(
        const signed char* __restrict__ A, const signed char* __restrict__ B,
        const float* __restrict__ qscale, const float* __restrict__ bias,
        const float* __restrict__ dqs, float* __restrict__ out) {
    __shared__ __align__(16) signed char smem_[5 * 32768];  // 160 KB
    signed char* smem = smem_;

    const int tid = threadIdx.x;
    const int wid = tid >> 6;   // 0..3
    const int lane = tid & 63;
    const int wm = wid >> 1;    // 0..1
    const int wn = wid & 1;     // 0..1
    const int l31 = lane & 31;
    const int hi = lane >> 5;

    // XCD map: XCD k owns m-tiles [4k,4k+4), sweeps n. Bijective (1376 = 8*172).
    const int b = (int)blockIdx.x;
    const int xcd = b & 7;
    const int idx = b >> 3;
    const int m0 = (xcd * 4 + (idx & 3)) * BM;
    const int n0 = (idx >> 2) * BN;

    // staging: wave w stages mblk/nblk {2w, 2w+1}, 8 gload_lds (1KB each)/tile
    const signed char* aS[2];
    const signed char* bS[2];
    int ldS[2];
#pragma unroll
    for (int j = 0; j < 2; ++j) {
        aS[j] = A + ((size_t)((m0 >> 5) + 2 * wid + j)) * 131072 + lane * 16;
        bS[j] = B + ((size_t)((n0 >> 5) + 2 * wid + j)) * 131072 + lane * 16;
        ldS[j] = (2 * wid + j) * 2048;  // wave-uniform; HW adds lane*16
    }
    // fragment read offsets (contiguous per wave -> conflict-free)
    int rdA[4], rdB[4];
#pragma unroll
    for (int im = 0; im < 4; ++im) rdA[im] = (wm * 4 + im) * 2048 + lane * 16;
#pragma unroll
    for (int in = 0; in < 4; ++in) rdB[in] = 16384 + (wn * 4 + in) * 2048 + lane * 16;

    v16i acc[4][4] = {};
    v4i a0[4][2], b0[4][2], a1[4][2], b1[4][2];

    // ---- prologue: stage tiles 0..3 into bufs 0..3 ----
#pragma unroll
    for (int tt = 0; tt < 4; ++tt)
#pragma unroll
        for (int j = 0; j < 2; ++j)
#pragma unroll
            for (int ks = 0; ks < 2; ++ks) {
                load_lds16(aS[j] + tt * 2048 + ks * 1024,
                           smem + tt * 32768 + ldS[j] + ks * 1024);
                load_lds16(bS[j] + tt * 2048 + ks * 1024,
                           smem + tt * 32768 + 16384 + ldS[j] + ks * 1024);
            }
    asm volatile("s_waitcnt vmcnt(24)" ::: "memory");  // tile 0 landed
    __builtin_amdgcn_sched_barrier(0);
    __builtin_amdgcn_s_barrier();
    __builtin_amdgcn_sched_barrier(0);
    // read frags(0) from buf0 into set0
#pragma unroll
    for (int im = 0; im < 4; ++im)
#pragma unroll
        for (int ks = 0; ks < 2; ++ks)
            a0[im][ks] = *(const v4i*)(smem + rdA[im] + ks * 1024);
#pragma unroll
    for (int in = 0; in < 4; ++in)
#pragma unroll
        for (int ks = 0; ks < 2; ++ks)
            b0[in][ks] = *(const v4i*)(smem + rdB[in] + ks * 1024);

    // PH: SB=stage buf, RB=read buf, CA/CB=compute set, NA/NB=load set,
    //     KT=stage tile idx, VMC=vmcnt, DOSTAGE/DOREAD flags.
#define PH(SB, RB, CA, CB, NA, NB, KT, VMC, DOSTAGE, DOREAD) do {              \
    if (DOSTAGE) {                                                             \
        const int ko_ = (KT) * 2048;                                           \
        _Pragma("unroll")                                                      \
        for (int j = 0; j < 2; ++j)                                            \
            _Pragma("unroll")                                                  \
            for (int ks = 0; ks < 2; ++ks) {                                   \
                load_lds16(aS[j] + ko_ + ks * 1024,                            \
                           smem + (SB) * 32768 + ldS[j] + ks * 1024);          \
                load_lds16(bS[j] + ko_ + ks * 1024,                            \
                           smem + (SB) * 32768 + 16384 + ldS[j] + ks * 1024);  \
            }                                                                  \
    }                                                                          \
    asm volatile("s_waitcnt vmcnt(" #VMC ") lgkmcnt(0)" ::: "memory");         \
    __builtin_amdgcn_sched_barrier(0);                                         \
    __builtin_amdgcn_s_barrier();                                              \
    __builtin_amdgcn_sched_barrier(0);                                         \
    if (DOREAD) {                                                              \
        const signed char* rb_ = smem + (RB) * 32768;                          \
        _Pragma("unroll")                                                      \
        for (int im = 0; im < 4; ++im)                                         \
            _Pragma("unroll")                                                  \
            for (int ks = 0; ks < 2; ++ks)                                     \
                NA[im][ks] = *(const v4i*)(rb_ + rdA[im] + ks * 1024);         \
        _Pragma("unroll")                                                      \
        for (int in = 0; in < 4; ++in)                                         \
            _Pragma("unroll")                                                  \
            for (int ks = 0; ks < 2; ++ks)                                     \
                NB[in][ks] = *(const v4i*)(rb_ + rdB[in] + ks * 1024);         \
    }                                                                          \
    _Pragma("unroll")                                                          \
    for (int ks = 0; ks < 2; ++ks)                                             \
        _Pragma("unroll")                                                      \
        for (int im = 0; im < 4; ++im)                                         \
            _Pragma("unroll")                                                  \
            for (int in = 0; in < 4; ++in)                                     \
                acc[im][in] = __builtin_amdgcn_mfma_i32_32x32x32_i8(           \
                    CA[im][ks], CB[in][ks], acc[im][in], 0, 0, 0);             \
} while (0)

    // main: 6 x 10 phases (p = 0..59), all buf indices static mod 5
    for (int p = 0; p < 60; p += 10) {
        PH(4, 1, a0, b0, a1, b1, p + 4,  24, 1, 1);
        PH(0, 2, a1, b1, a0, b0, p + 5,  24, 1, 1);
        PH(1, 3, a0, b0, a1, b1, p + 6,  24, 1, 1);
        PH(2, 4, a1, b1, a0, b0, p + 7,  24, 1, 1);
        PH(3, 0, a0, b0, a1, b1, p + 8,  24, 1, 1);
        PH(4, 1, a1, b1, a0, b0, p + 9,  24, 1, 1);
        PH(0, 2, a0, b0, a1, b1, p + 10, 24, 1, 1);
        PH(1, 3, a1, b1, a0, b0, p + 11, 24, 1, 1);
        PH(2, 4, a0, b0, a1, b1, p + 12, 24, 1, 1);
        PH(3, 0, a1, b1, a0, b0, p + 13, 24, 1, 1);
    }
    // tail: p = 60..63 (no staging; drain 24 -> 16 -> 8 -> 0)
    PH(0, 1, a0, b0, a1, b1, 0, 16, 0, 1);
    PH(0, 2, a1, b1, a0, b0, 0, 8,  0, 1);
    PH(0, 3, a0, b0, a1, b1, 0, 0,  0, 1);
    PH(0, 4, a1, b1, a0, b0, 0, 0,  0, 0);
#undef PH

    // ---- epilogue: dequant + bias ----
    const float dq = dqs[0];
#pragma unroll
    for (int im = 0; im < 4; ++im) {
        float qsv[16];
#pragma unroll
        for (int r = 0; r < 16; ++r) {
            const int trow = wm * 128 + im * 32 + (r & 3) + 8 * (r >> 2) + 4 * hi;
            qsv[r] = dq * qscale[m0 + trow];
        }
#pragma unroll
        for (int in = 0; in < 4; ++in) {
            const int col = n0 + wn * 128 + in * 32 + l31;
            const float bv = bias[col];
#pragma unroll
            for (int r = 0; r < 16; ++r) {
                const int trow = wm * 128 + im * 32 + (r & 3) + 8 * (r >> 2) + 4 * hi;
                out[(size_t)(m0 + trow) * OUT_F + col] =
                    qsv[r] * (float)acc[im][in][r] + bv;
            }
        }
    }
}

extern "C" void kernel_launch(void* const* d_in, const int* in_sizes, int n_in,
                              void* d_out, int out_size, void* d_ws, size_t ws_size,
                              hipStream_t stream) {
    const float* x    = (const float*)d_in[0];
    const int*   w32  = (const int*)d_in[1];   // int8 values stored as int32
    const float* bias = (const float*)d_in[2];
    const float* dqs  = (const float*)d_in[3];
    float* out = (float*)d_out;

    signed char* xq = (signed char*)d_ws;                                   // 33.55 MB
    float* qscale   = (float*)((char*)d_ws + (size_t)T_TOKENS * IN_F);      // 32 KB
    signed char* w8 = (signed char*)((char*)d_ws + (size_t)T_TOKENS * IN_F
                                     + (size_t)T_TOKENS * 4);               // 45.1 MB

    quant_repack_kernel<<<T_TOKENS + (OUT_F / 32) * 32, 256, 0, stream>>>(
        x, xq, qscale, w32, w8);
    dim3 g((T_TOKENS / BM) * (OUT_F / BN));  // 1376
    gemm_kernel<<<g, 256, 0, stream>>>(xq, w8, qscale, bias, dqs, out);
}